// Round 4
// baseline (6437.629 us; speedup 1.0000x reference)
//
#include <hip/hip_runtime.h>

#define DEVI __device__ __forceinline__

typedef __attribute__((ext_vector_type(8))) short bf8;
typedef __attribute__((ext_vector_type(4))) float f4;

DEVI unsigned short f2bf(float f) {
  union { float f; unsigned u; } v; v.f = f;
  unsigned r = v.u + 0x7fffu + ((v.u >> 16) & 1u);
  return (unsigned short)(r >> 16);
}
DEVI float bf2f(unsigned short b) {
  union { unsigned u; float f; } v; v.u = ((unsigned)b) << 16;
  return v.f;
}
DEVI float sigmoidf_(float x) { return 1.f / (1.f + __expf(-x)); }
DEVI float tanhf_(float x) {
  float ax = fabsf(x);
  float e = __expf(-2.f * ax);
  float t = (1.f - e) / (1.f + e);
  return x < 0.f ? -t : t;
}

#define GLDS16(g, l) __builtin_amdgcn_global_load_lds( \
    (const __attribute__((address_space(1))) void*)(g), \
    (__attribute__((address_space(3))) void*)(l), 16, 0, 0)

// ---------------- conversion kernels ----------------

__global__ void k_conv_emb(const float* __restrict__ emb, unsigned short* __restrict__ ep) {
  int i = blockIdx.x * 256 + threadIdx.x;            // 10000 * 128
  if (i >= 10000 * 128) return;
  int r = i >> 7, c = i & 127;
  ep[i] = (c < 100) ? f2bf(emb[r * 100 + c]) : (unsigned short)0;
}

// column permutation: original col n = gate*1024 + u  ->
// n' = (u/32)*128 + ((u%32)/16)*64 + gate*16 + (u%16)
DEVI int permn(int n) {
  int g = n >> 10, u = n & 1023;
  return (u >> 5) * 128 + ((u >> 4) & 1) * 64 + g * 16 + (u & 15);
}

__global__ void k_conv_w0(const float* __restrict__ W0, const float* __restrict__ U0,
                          unsigned short* __restrict__ WT) {
  int i = blockIdx.x * 256 + threadIdx.x;            // 4096 * 1152
  if (i >= 4096 * 1152) return;
  int n = i / 1152, k = i - n * 1152;
  float v;
  if (k < 100) v = W0[k * 4096 + n];
  else if (k < 128) v = 0.f;
  else v = U0[(k - 128) * 4096 + n];
  WT[(size_t)permn(n) * 1152 + k] = f2bf(v);
}

__global__ void k_conv_w1(const float* __restrict__ W1, const float* __restrict__ U1,
                          unsigned short* __restrict__ WT) {
  int i = blockIdx.x * 256 + threadIdx.x;            // 4096 * 2048
  if (i >= 4096 * 2048) return;
  int n = i >> 11, k = i & 2047;
  float v = (k < 1024) ? W1[k * 4096 + n] : U1[(k - 1024) * 4096 + n];
  WT[(size_t)permn(n) * 2048 + k] = f2bf(v);
}

// ---------------- fused LSTM step body --------------------------------------
// BK=32, double-buffered (32 KB LDS/block -> up to 4 blocks/CU resident).
// Prefetch-after-barrier: stage(0); for kb { __syncthreads(); stage(kb+1);
// compute(kb); }.
// Swizzle (4 chunks of 16B per 64B row): physical chunk = chunk ^ (row&3),
// applied on the global side at staging; readers XOR with (cl&3).
// Staging addresses are (uniform base + voff) so the compiler emits
// saddr+voffset global_load_lds — cuts vector pointer registers.

template<int K1, int KTOT, bool GATHER>
DEVI void lstm_body(int blk, char* smem,
    const unsigned short* __restrict__ src1,   // embp (gathered) or h0(t-1)
    const unsigned short* __restrict__ src2,   // h prev (recurrent input)
    const int* __restrict__ idx, int t,
    const unsigned short* __restrict__ WT,     // [4096][KTOT] bf16, permuted rows
    const float* __restrict__ bias,            // [4096] original layout
    float* __restrict__ cbuf,                  // [2048][1024] fp32, in-place
    unsigned short* __restrict__ hout)         // [2048][1024] bf16
{
  const int tid = threadIdx.x;
  const int bn = blk & 31;
  const int bm = blk >> 5;
  const int m0 = bm * 128;
  const int n0 = bn * 128;

  const int lr = tid >> 2;                       // staging row-in-pass 0..63
  const int k8 = ((tid & 3) ^ (lr & 3)) * 8;     // swizzled chunk offset (elems)

  const int voffA = lr * 1024 + k8;              // stride-1024 sources
  const int voffB = lr * KTOT + k8;

  const unsigned short* g1[2];                   // gathered src1 rows
  if (GATHER) {
#pragma unroll
    for (int p = 0; p < 2; ++p) {
      int grow = idx[(m0 + p * 64 + lr) * 80 + t];
      g1[p] = src1 + (size_t)grow * K1 + k8;
    }
  }

  unsigned short* const LA0 = (unsigned short*)smem;
  unsigned short* const LB0 = (unsigned short*)(smem + 8192);
  unsigned short* const LA1 = (unsigned short*)(smem + 16384);
  unsigned short* const LB1 = (unsigned short*)(smem + 24576);

  auto stage = [&](int kb) {
    unsigned short* la = (kb & 1) ? LA1 : LA0;
    unsigned short* lb = (kb & 1) ? LB1 : LB0;
    const int kc = kb * 32;
    if (kc < K1) {
      if (GATHER) {
#pragma unroll
        for (int p = 0; p < 2; ++p)
          GLDS16(g1[p] + kc, &la[p * 2048 + tid * 8]);
      } else {
#pragma unroll
        for (int p = 0; p < 2; ++p)
          GLDS16(src1 + (size_t)(m0 + p * 64) * 1024 + kc + voffA,
                 &la[p * 2048 + tid * 8]);
      }
    } else {
#pragma unroll
      for (int p = 0; p < 2; ++p)
        GLDS16(src2 + (size_t)(m0 + p * 64) * 1024 + (kc - K1) + voffA,
               &la[p * 2048 + tid * 8]);
    }
#pragma unroll
    for (int p = 0; p < 2; ++p)
      GLDS16(WT + (size_t)(n0 + p * 64) * KTOT + kc + voffB,
             &lb[p * 2048 + tid * 8]);
  };

  const int lane = tid & 63;
  const int wv = tid >> 6;
  const int wm = wv >> 1;     // wave m-half (0..1)
  const int wn = wv & 1;      // wave n-half (0..1)
  const int cl = lane & 15;
  const int qd = lane >> 4;
  const int swr = (cl & 3) * 8;  // read-side XOR, pre-scaled to elements

  f4 acc[4][4];
  const f4 fz = {0.f, 0.f, 0.f, 0.f};
#pragma unroll
  for (int a = 0; a < 4; ++a)
#pragma unroll
    for (int b = 0; b < 4; ++b) acc[a][b] = fz;

  stage(0);

  constexpr int NKB = KTOT / 32;
#pragma unroll 1
  for (int kb = 0; kb < NKB; ++kb) {
    __syncthreads();                      // drains only last iter's loads
    if (kb + 1 < NKB) stage(kb + 1);      // prefetch next K-block
    unsigned short* la = (kb & 1) ? LA1 : LA0;
    unsigned short* lb = (kb & 1) ? LB1 : LB0;
    bf8 af[4], bfr[4];
#pragma unroll
    for (int mi = 0; mi < 4; ++mi)
      af[mi] = *(const bf8*)&la[(wm * 64 + mi * 16 + cl) * 32 + ((qd * 8) ^ swr)];
#pragma unroll
    for (int j = 0; j < 4; ++j)
      bfr[j] = *(const bf8*)&lb[(wn * 64 + j * 16 + cl) * 32 + ((qd * 8) ^ swr)];
#pragma unroll
    for (int mi = 0; mi < 4; ++mi)
#pragma unroll
      for (int j = 0; j < 4; ++j)
        acc[mi][j] = __builtin_amdgcn_mfma_f32_16x16x32_bf16(
            af[mi], bfr[j], acc[mi][j], 0, 0, 0);
  }

  // epilogue: per-lane holds z_i, z_f, z_g, z_o (j = gate) for unit u
  const int u = bn * 32 + wn * 16 + cl;
  const float bi = bias[u];
  const float bff = bias[1024 + u];
  const float bg = bias[2048 + u];
  const float bo = bias[3072 + u];
#pragma unroll
  for (int mi = 0; mi < 4; ++mi) {
    int mbase = m0 + wm * 64 + mi * 16 + qd * 4;
#pragma unroll
    for (int r = 0; r < 4; ++r) {
      int m = mbase + r;
      float gi = sigmoidf_(acc[mi][0][r] + bi);
      float gf = sigmoidf_(acc[mi][1][r] + bff);
      float gg = tanhf_(acc[mi][2][r] + bg);
      float go = sigmoidf_(acc[mi][3][r] + bo);
      size_t off = (size_t)m * 1024 + u;
      float cn = gf * cbuf[off] + gi * gg;
      cbuf[off] = cn;
      hout[off] = f2bf(go * tanhf_(cn));
    }
  }
}

// mode 0: layer-0 only (grid 512). mode 1: fused, even blocks = layer-1(t-1),
// odd = layer-0(t) (grid 1024). mode 2: layer-1 only (grid 512).
__global__ __launch_bounds__(256, 4) void k_step(
    int mode,
    const unsigned short* embp, const unsigned short* h0in,
    const int* idx, int t,
    const unsigned short* WT0, const float* b0, float* c0, unsigned short* h0out,
    const unsigned short* h0prev, const unsigned short* h1in,
    const unsigned short* WT1, const float* b1, float* c1, unsigned short* h1out)
{
  extern __shared__ char smem[];
  const int blk = blockIdx.x;
  const int tile = (mode == 1) ? (blk >> 1) : blk;
  const bool isL0 = (mode == 0) || (mode == 1 && (blk & 1));
  if (isL0)
    lstm_body<128, 1152, true>(tile, smem, embp, h0in, idx, t,
                               WT0, b0, c0, h0out);
  else
    lstm_body<1024, 2048, false>(tile, smem, h0prev, h1in, nullptr, 0,
                                 WT1, b1, c1, h1out);
}

// ---------------- final FC + sigmoid ----------------

__global__ void k_fc(const unsigned short* __restrict__ h1,
                     const float* __restrict__ fcW, const float* __restrict__ fcb,
                     float* __restrict__ out) {
  int wv = threadIdx.x >> 6;
  int lane = threadIdx.x & 63;
  int row = blockIdx.x * 4 + wv;
  if (row >= 2048) return;
  const unsigned short* hr = h1 + (size_t)row * 1024;
  float s = 0.f;
  for (int k = lane; k < 1024; k += 64) s += bf2f(hr[k]) * fcW[k];
#pragma unroll
  for (int off = 32; off > 0; off >>= 1) s += __shfl_down(s, off);
  if (lane == 0) out[row] = sigmoidf_(s + fcb[0]);
}

// ---------------- launcher ----------------

extern "C" void kernel_launch(void* const* d_in, const int* in_sizes, int n_in,
                              void* d_out, int out_size, void* d_ws, size_t ws_size,
                              hipStream_t stream) {
  const int*   idx = (const int*)d_in[0];
  const float* emb = (const float*)d_in[1];
  const float* W0  = (const float*)d_in[2];
  const float* U0  = (const float*)d_in[3];
  const float* b0  = (const float*)d_in[4];
  const float* W1  = (const float*)d_in[5];
  const float* U1  = (const float*)d_in[6];
  const float* b1  = (const float*)d_in[7];
  const float* fcW = (const float*)d_in[8];
  const float* fcb = (const float*)d_in[9];
  float* out = (float*)d_out;

  char* ws = (char*)d_ws;
  unsigned short* embp = (unsigned short*)(ws);                    //  2,560,000
  unsigned short* WT0  = (unsigned short*)(ws + 2560000);          //  9,437,184
  unsigned short* WT1  = (unsigned short*)(ws + 11997184);         // 16,777,216
  unsigned short* h0b[2] = {(unsigned short*)(ws + 28774400),
                            (unsigned short*)(ws + 32968704)};     // 2x 4,194,304
  unsigned short* h1b[2] = {(unsigned short*)(ws + 37163008),
                            (unsigned short*)(ws + 41357312)};     // 2x 4,194,304
  float* c0 = (float*)(ws + 45551616);                             //  8,388,608
  float* c1 = (float*)(ws + 53940224);                             //  8,388,608
  // total: 62,328,832 bytes

  // zero h (both buffers of both layers) and c
  hipMemsetAsync(ws + 28774400, 0, 33554432, stream);

  k_conv_emb<<<5000, 256, 0, stream>>>(emb, embp);
  k_conv_w0<<<18432, 256, 0, stream>>>(W0, U0, WT0);
  k_conv_w1<<<32768, 256, 0, stream>>>(W1, U1, WT1);

  // t = 0: layer-0 only
  k_step<<<512, 256, 32768, stream>>>(0, embp, h0b[1], idx, 0,
                                      WT0, b0, c0, h0b[0],
                                      nullptr, nullptr, WT1, b1, c1, nullptr);
  // t = 1..79: fused [layer-1(t-1) | layer-0(t)]
  for (int t = 1; t < 80; ++t) {
    k_step<<<1024, 256, 32768, stream>>>(1, embp, h0b[(t + 1) & 1], idx, t,
                                         WT0, b0, c0, h0b[t & 1],
                                         h0b[(t - 1) & 1], h1b[t & 1],
                                         WT1, b1, c1, h1b[(t + 1) & 1]);
  }
  // final: layer-1 at t=79 (src1 = h0b[1], in h1b[0], out h1b[1])
  k_step<<<512, 256, 32768, stream>>>(2, nullptr, nullptr, nullptr, 0,
                                      WT0, b0, c0, nullptr,
                                      h0b[1], h1b[0], WT1, b1, c1, h1b[1]);

  k_fc<<<512, 256, 0, stream>>>(h1b[1], fcW, fcb, out);
}

// Round 5
// 4273.751 us; speedup vs baseline: 1.5063x; 1.5063x over previous
//
#include <hip/hip_runtime.h>

#define DEVI __device__ __forceinline__

typedef __attribute__((ext_vector_type(4))) float f4;
typedef long long i64t;

DEVI unsigned char f2fp8(float x) {
  int p = __builtin_amdgcn_cvt_pk_fp8_f32(x, x, 0, false);
  return (unsigned char)(p & 0xff);
}
DEVI float fp82f(unsigned char b) {
  return __builtin_amdgcn_cvt_f32_fp8((int)b, 0);
}
DEVI float sigmoidf_(float x) { return 1.f / (1.f + __expf(-x)); }
DEVI float tanhf_(float x) {
  float ax = fabsf(x);
  float e = __expf(-2.f * ax);
  float t = (1.f - e) / (1.f + e);
  return x < 0.f ? -t : t;
}

#define GLDS16(g, l) __builtin_amdgcn_global_load_lds( \
    (const __attribute__((address_space(1))) void*)(g), \
    (__attribute__((address_space(3))) void*)(l), 16, 0, 0)

// All GEMM operands are fp8 e4m3 scaled by 64 (raw values ~N(0,0.02) are
// subnormal in e4m3; x64 centers them in the normal range). acc = 4096*z;
// epilogue multiplies by 1/4096.
#define SCALE_UP 64.0f
#define SCALE_DN (1.0f / 4096.0f)

// ---------------- conversion kernels ----------------

__global__ void k_conv_emb(const float* __restrict__ emb, unsigned char* __restrict__ ep) {
  int i = blockIdx.x * 256 + threadIdx.x;            // 10000 * 128
  if (i >= 10000 * 128) return;
  int r = i >> 7, c = i & 127;
  ep[i] = (c < 100) ? f2fp8(emb[r * 100 + c] * SCALE_UP) : (unsigned char)0;
}

// column permutation: original col n = gate*1024 + u  ->
// n' = (u/32)*128 + ((u%32)/16)*64 + gate*16 + (u%16)
DEVI int permn(int n) {
  int g = n >> 10, u = n & 1023;
  return (u >> 5) * 128 + ((u >> 4) & 1) * 64 + g * 16 + (u & 15);
}
// bank swizzle baked into storage: within each 64B k-block, 16B chunk c of
// row n' holds logical chunk c ^ ((n'>>2)&3)
DEVI int kswz(int klog, int row) {
  return (klog & ~63) | ((((klog >> 4) & 3) ^ ((row >> 2) & 3)) << 4) | (klog & 15);
}

__global__ void k_conv_w0(const float* __restrict__ W0, const float* __restrict__ U0,
                          unsigned char* __restrict__ WT) {
  int i = blockIdx.x * 256 + threadIdx.x;            // 4096 * 1152
  if (i >= 4096 * 1152) return;
  int n = i / 1152, k = i - n * 1152;
  float v;
  if (k < 100) v = W0[k * 4096 + n];
  else if (k < 128) v = 0.f;
  else v = U0[(k - 128) * 4096 + n];
  int np = permn(n);
  WT[(size_t)np * 1152 + kswz(k, np)] = f2fp8(v * SCALE_UP);
}

__global__ void k_conv_w1(const float* __restrict__ W1, const float* __restrict__ U1,
                          unsigned char* __restrict__ WT) {
  int i = blockIdx.x * 256 + threadIdx.x;            // 4096 * 2048
  if (i >= 4096 * 2048) return;
  int n = i >> 11, k = i & 2047;
  float v = (k < 1024) ? W1[k * 4096 + n] : U1[(k - 1024) * 4096 + n];
  int np = permn(n);
  WT[(size_t)np * 2048 + kswz(k, np)] = f2fp8(v * SCALE_UP);
}

// ---------------- fused LSTM step body (fp8) --------------------------------
// 128x128 tile, BK=64 bytes, double-buffered (32 KB LDS -> 4 blocks/CU).
// h and WT storage carry the 16B-granule bank swizzle (f(r) = (r>>2)&3), so
// staging is plain contiguous 16B chunks; only gathered embp XORs at stage
// time. Readers (ds_read_b64) XOR the 16B-chunk index with (cl>>2)&3.

template<int K1, int KTOT, bool GATHER>
DEVI void lstm_body(int blk, char* smem,
    const unsigned char* __restrict__ src1,   // embp (gathered) or h0(t-1)
    const unsigned char* __restrict__ src2,   // h prev (recurrent input)
    const int* __restrict__ idx, int t,
    const unsigned char* __restrict__ WT,     // [4096][KTOT] fp8, perm+swz
    const float* __restrict__ bias,           // [4096] original layout
    float* __restrict__ cbuf,                 // [2048][1024] fp32, in-place
    unsigned char* __restrict__ hout)         // [2048][1024] fp8 x64, swz
{
  const int tid = threadIdx.x;
  const int bn = blk & 31;
  const int bm = blk >> 5;
  const int m0 = bm * 128;
  const int n0 = bn * 128;

  const int lr = tid >> 2;                 // staging row-in-pass 0..63
  const int c16 = (tid & 3) * 16;          // plain 16B chunk offset
  const int csw = (((tid & 3) ^ ((tid >> 4) & 3))) * 16;  // swizzled (embp)

  const unsigned char* g1[2];              // gathered embp rows (pre-offset)
  if (GATHER) {
#pragma unroll
    for (int p = 0; p < 2; ++p) {
      int w = idx[(m0 + p * 64 + lr) * 80 + t];
      g1[p] = src1 + (size_t)w * K1 + csw;
    }
  }

  char* const LA0 = smem;
  char* const LB0 = smem + 8192;
  char* const LA1 = smem + 16384;
  char* const LB1 = smem + 24576;

  auto stage = [&](int kb) {
    char* la = (kb & 1) ? LA1 : LA0;
    char* lb = (kb & 1) ? LB1 : LB0;
    const int kc = kb * 64;
    if (GATHER && kc < K1) {
#pragma unroll
      for (int p = 0; p < 2; ++p)
        GLDS16(g1[p] + kc, la + p * 4096 + tid * 16);
    } else {
#pragma unroll
      for (int p = 0; p < 2; ++p) {
        size_t row = (size_t)(m0 + p * 64 + lr);
        const unsigned char* g = (kc < K1)
            ? (src1 + row * 1024 + kc + c16)
            : (src2 + row * 1024 + (kc - K1) + c16);
        GLDS16(g, la + p * 4096 + tid * 16);
      }
    }
#pragma unroll
    for (int p = 0; p < 2; ++p)
      GLDS16(WT + (size_t)(n0 + p * 64 + lr) * KTOT + kc + c16,
             lb + p * 4096 + tid * 16);
  };

  const int lane = tid & 63;
  const int wv = tid >> 6;
  const int wm = wv >> 1;     // wave m-half (0..1)
  const int wn = wv & 1;      // wave n-half (0..1)
  const int cl = lane & 15;
  const int qd = lane >> 4;
  const int qh = qd >> 1, qb = qd & 1;
  const int fcl = (cl >> 2) & 3;
  // byte offset within a 64B row for kk=0/1 fragment reads
  const int koff0 = ((qh ^ fcl) << 4) + qb * 8;
  const int koff1 = (((2 + qh) ^ fcl) << 4) + qb * 8;

  f4 acc[4][4];
  const f4 fz = {0.f, 0.f, 0.f, 0.f};
#pragma unroll
  for (int a = 0; a < 4; ++a)
#pragma unroll
    for (int b = 0; b < 4; ++b) acc[a][b] = fz;

  stage(0);

  constexpr int NKB = KTOT / 64;
#pragma unroll 1
  for (int kb = 0; kb < NKB; ++kb) {
    __syncthreads();                      // drains only last iter's loads
    if (kb + 1 < NKB) stage(kb + 1);      // prefetch next K-block
    char* la = (kb & 1) ? LA1 : LA0;
    char* lb = (kb & 1) ? LB1 : LB0;
#pragma unroll
    for (int kk = 0; kk < 2; ++kk) {
      const int ko = kk ? koff1 : koff0;
      i64t af[4], bfr[4];
#pragma unroll
      for (int mi = 0; mi < 4; ++mi)
        af[mi] = *(const i64t*)(la + (wm * 64 + mi * 16 + cl) * 64 + ko);
#pragma unroll
      for (int j = 0; j < 4; ++j)
        bfr[j] = *(const i64t*)(lb + (wn * 64 + j * 16 + cl) * 64 + ko);
#pragma unroll
      for (int mi = 0; mi < 4; ++mi)
#pragma unroll
        for (int j = 0; j < 4; ++j)
          acc[mi][j] = __builtin_amdgcn_mfma_f32_16x16x32_fp8_fp8(
              af[mi], bfr[j], acc[mi][j], 0, 0, 0);
    }
  }

  // epilogue: per-lane holds z_i, z_f, z_g, z_o (j = gate) for unit u.
  // h column swizzle: f(m) = (m>>2)&3 = qd for every row this lane owns.
  const int u = bn * 32 + wn * 16 + cl;
  const int hcol = (u & ~63) | (((((u >> 4) & 3) ^ qd)) << 4) | (u & 15);
  const float bi = bias[u];
  const float bff = bias[1024 + u];
  const float bg = bias[2048 + u];
  const float bo = bias[3072 + u];
#pragma unroll
  for (int mi = 0; mi < 4; ++mi) {
    int mbase = m0 + wm * 64 + mi * 16 + qd * 4;
#pragma unroll
    for (int r = 0; r < 4; ++r) {
      int m = mbase + r;
      float gi = sigmoidf_(acc[mi][0][r] * SCALE_DN + bi);
      float gf = sigmoidf_(acc[mi][1][r] * SCALE_DN + bff);
      float gg = tanhf_(acc[mi][2][r] * SCALE_DN + bg);
      float go = sigmoidf_(acc[mi][3][r] * SCALE_DN + bo);
      size_t coff = (size_t)m * 1024 + u;
      float cn = gf * cbuf[coff] + gi * gg;
      cbuf[coff] = cn;
      hout[(size_t)m * 1024 + hcol] = f2fp8(go * tanhf_(cn) * SCALE_UP);
    }
  }
}

// mode 0: layer-0 only (grid 512). mode 1: fused, even blocks = layer-1(t-1),
// odd = layer-0(t) (grid 1024). mode 2: layer-1 only (grid 512).
__global__ __launch_bounds__(256, 4) void k_step(
    int mode,
    const unsigned char* embp, const unsigned char* h0in,
    const int* idx, int t,
    const unsigned char* WT0, const float* b0, float* c0, unsigned char* h0out,
    const unsigned char* h0prev, const unsigned char* h1in,
    const unsigned char* WT1, const float* b1, float* c1, unsigned char* h1out)
{
  extern __shared__ char smem[];
  const int blk = blockIdx.x;
  const int tile = (mode == 1) ? (blk >> 1) : blk;
  const bool isL0 = (mode == 0) || (mode == 1 && (blk & 1));
  if (isL0)
    lstm_body<128, 1152, true>(tile, smem, embp, h0in, idx, t,
                               WT0, b0, c0, h0out);
  else
    lstm_body<1024, 2048, false>(tile, smem, h0prev, h1in, nullptr, 0,
                                 WT1, b1, c1, h1out);
}

// ---------------- final FC + sigmoid ----------------

__global__ void k_fc(const unsigned char* __restrict__ h1,
                     const float* __restrict__ fcW, const float* __restrict__ fcb,
                     float* __restrict__ out) {
  int wv = threadIdx.x >> 6;
  int lane = threadIdx.x & 63;
  int row = blockIdx.x * 4 + wv;
  if (row >= 2048) return;
  const unsigned char* hr = h1 + (size_t)row * 1024;
  const int f = (row >> 2) & 3;
  float s = 0.f;
  for (int k = lane; k < 1024; k += 64) {
    int ks = (k & ~63) | ((((k >> 4) & 3) ^ f) << 4) | (k & 15);
    s += fp82f(hr[ks]) * fcW[k];
  }
#pragma unroll
  for (int off = 32; off > 0; off >>= 1) s += __shfl_down(s, off);
  if (lane == 0) out[row] = sigmoidf_(s * (1.0f / SCALE_UP) + fcb[0]);
}

// ---------------- launcher ----------------

extern "C" void kernel_launch(void* const* d_in, const int* in_sizes, int n_in,
                              void* d_out, int out_size, void* d_ws, size_t ws_size,
                              hipStream_t stream) {
  const int*   idx = (const int*)d_in[0];
  const float* emb = (const float*)d_in[1];
  const float* W0  = (const float*)d_in[2];
  const float* U0  = (const float*)d_in[3];
  const float* b0  = (const float*)d_in[4];
  const float* W1  = (const float*)d_in[5];
  const float* U1  = (const float*)d_in[6];
  const float* b1  = (const float*)d_in[7];
  const float* fcW = (const float*)d_in[8];
  const float* fcb = (const float*)d_in[9];
  float* out = (float*)d_out;

  char* ws = (char*)d_ws;
  unsigned char* embp = (unsigned char*)(ws);                   //  1,280,000
  unsigned char* WT0  = (unsigned char*)(ws + 1280000);         //  4,718,592
  unsigned char* WT1  = (unsigned char*)(ws + 5998592);         //  8,388,608
  unsigned char* h0b[2] = {(unsigned char*)(ws + 14387200),
                           (unsigned char*)(ws + 16484352)};    // 2x 2,097,152
  unsigned char* h1b[2] = {(unsigned char*)(ws + 18581504),
                           (unsigned char*)(ws + 20678656)};    // 2x 2,097,152
  float* c0 = (float*)(ws + 22775808);                          //  8,388,608
  float* c1 = (float*)(ws + 31164416);                          //  8,388,608
  // total: 39,553,024 bytes

  // zero h (4 buffers) and c0/c1 — contiguous region
  hipMemsetAsync(ws + 14387200, 0, 25165824, stream);

  k_conv_emb<<<5000, 256, 0, stream>>>(emb, embp);
  k_conv_w0<<<18432, 256, 0, stream>>>(W0, U0, WT0);
  k_conv_w1<<<32768, 256, 0, stream>>>(W1, U1, WT1);

  // t = 0: layer-0 only
  k_step<<<512, 256, 32768, stream>>>(0, embp, h0b[1], idx, 0,
                                      WT0, b0, c0, h0b[0],
                                      nullptr, nullptr, WT1, b1, c1, nullptr);
  // t = 1..79: fused [layer-1(t-1) | layer-0(t)]
  for (int t = 1; t < 80; ++t) {
    k_step<<<1024, 256, 32768, stream>>>(1, embp, h0b[(t + 1) & 1], idx, t,
                                         WT0, b0, c0, h0b[t & 1],
                                         h0b[(t - 1) & 1], h1b[t & 1],
                                         WT1, b1, c1, h1b[(t + 1) & 1]);
  }
  // final: layer-1 at t=79 (src1 = h0b[1], in h1b[0], out h1b[1])
  k_step<<<512, 256, 32768, stream>>>(2, nullptr, nullptr, nullptr, 0,
                                      WT0, b0, c0, nullptr,
                                      h0b[1], h1b[0], WT1, b1, c1, h1b[1]);

  k_fc<<<512, 256, 0, stream>>>(h1b[1], fcW, fcb, out);
}